// Round 6
// baseline (2261.843 us; speedup 1.0000x reference)
//
#include <hip/hip_runtime.h>

typedef unsigned short u16;
typedef __bf16 bf16x8 __attribute__((ext_vector_type(8)));
typedef float f32x4 __attribute__((ext_vector_type(4)));

#define T_TOK 200704   // 4*224*224
#define NTOK 49
#define SA 264         // stride (u16) for [49][256] LDS tiles
#define SP 72          // P per-head row stride

__device__ __forceinline__ u16 f2bf(float f) {
    union { float f; unsigned u; } v; v.f = f;
    return (u16)((v.u + 0x7FFFu + ((v.u >> 16) & 1u)) >> 16);
}
__device__ __forceinline__ bf16x8 zfrag() {
    bf16x8 z;
#pragma unroll
    for (int i = 0; i < 8; ++i) z[i] = (__bf16)0.0f;
    return z;
}

// ---------------- transpose fp32 (K x N) -> bf16 (N x K) ----------------
__global__ void k_transpose(const float* __restrict__ in, u16* __restrict__ out, int K, int N) {
    int idx = blockIdx.x * blockDim.x + threadIdx.x;
    if (idx >= K * N) return;
    int k = idx / N, n = idx - k * N;
    out[n * K + k] = f2bf(in[idx]);
}

// Half-height GEMM: rows [mtb*16, mtb*16+31] of out(49x256) = A(49x256) @ W,
// strip cols [nb, nb+63]. A in LDS row-major stride SA. WT bf16 global [n][k].
__device__ __forceinline__ void gemm49h(const u16* A, const u16* WT,
                                        int nb, int mtb, int lane, f32x4 acc[2][4]) {
    const int ar = lane & 15;
    const int kg = (lane >> 4) * 8;
    const bf16x8 z = zfrag();
    for (int k0 = 0; k0 < 256; k0 += 32) {
        bf16x8 a[2], bb[4];
#pragma unroll
        for (int m = 0; m < 2; ++m) {
            int row = (mtb + m) * 16 + ar;
            a[m] = (row < NTOK) ? *(const bf16x8*)(A + row * SA + k0 + kg) : z;
        }
#pragma unroll
        for (int nt = 0; nt < 4; ++nt) {
            int col = nb + nt * 16 + ar;
            bb[nt] = *(const bf16x8*)(WT + col * 256 + k0 + kg);
        }
#pragma unroll
        for (int m = 0; m < 2; ++m)
#pragma unroll
            for (int nt = 0; nt < 4; ++nt)
                acc[m][nt] = __builtin_amdgcn_mfma_f32_16x16x32_bf16(a[m], bb[nt], acc[m][nt], 0, 0, 0);
    }
}

// ---------------- dense KV projection GEMM ----------------
// grid (T_TOK/64, 4), block 256 (4 waves). KV[token][1024] bf16:
// cols 0-255 = enc@wk1+bk1, 256-511 = enc@wv1+bv1, 512-767 = K2, 768-1023 = V2.
__global__ __launch_bounds__(256, 4) void k_kv(
    const float* __restrict__ enc, u16* __restrict__ KV,
    const u16* __restrict__ w0T, const u16* __restrict__ w1T,
    const u16* __restrict__ w2T, const u16* __restrict__ w3T,
    const float* __restrict__ b0, const float* __restrict__ b1,
    const float* __restrict__ b2, const float* __restrict__ b3)
{
    __shared__ __align__(16) u16 aL[64 * SA];
    const int tid = threadIdx.x, lane = tid & 63, w = tid >> 6;
    const int gy = blockIdx.y;
    const u16* WT = (gy == 0) ? w0T : (gy == 1) ? w1T : (gy == 2) ? w2T : w3T;
    const float* bs = (gy == 0) ? b0 : (gy == 1) ? b1 : (gy == 2) ? b2 : b3;
    const size_t t0 = (size_t)blockIdx.x * 64;

    for (int idx = tid; idx < 64 * 32; idx += 256) {
        int r = idx >> 5, c8 = (idx & 31) << 3;
        const float* ep = enc + (t0 + r) * 256 + c8;
        const float4 v0 = *(const float4*)ep;
        const float4 v1 = *(const float4*)(ep + 4);
        u16* p = aL + r * SA + c8;
        p[0] = f2bf(v0.x); p[1] = f2bf(v0.y); p[2] = f2bf(v0.z); p[3] = f2bf(v0.w);
        p[4] = f2bf(v1.x); p[5] = f2bf(v1.y); p[6] = f2bf(v1.z); p[7] = f2bf(v1.w);
    }
    __syncthreads();

    const int nb = w * 64, ar = lane & 15, g = lane >> 4, kg = g * 8;
    f32x4 acc[4][4] = {};
    for (int k0 = 0; k0 < 256; k0 += 32) {
        bf16x8 a[4], bb[4];
#pragma unroll
        for (int mt = 0; mt < 4; ++mt)
            a[mt] = *(const bf16x8*)(aL + (mt * 16 + ar) * SA + k0 + kg);
#pragma unroll
        for (int nt = 0; nt < 4; ++nt)
            bb[nt] = *(const bf16x8*)(WT + (nb + nt * 16 + ar) * 256 + k0 + kg);
#pragma unroll
        for (int mt = 0; mt < 4; ++mt)
#pragma unroll
            for (int nt = 0; nt < 4; ++nt)
                acc[mt][nt] = __builtin_amdgcn_mfma_f32_16x16x32_bf16(a[mt], bb[nt], acc[mt][nt], 0, 0, 0);
    }
#pragma unroll
    for (int mt = 0; mt < 4; ++mt)
#pragma unroll
        for (int nt = 0; nt < 4; ++nt) {
            int col = nb + nt * 16 + (lane & 15);
            float bias = bs[col];
#pragma unroll
            for (int r = 0; r < 4; ++r) {
                int row = mt * 16 + g * 4 + r;
                KV[(t0 + row) * 1024 + gy * 256 + col] = f2bf(acc[mt][nt][r] + bias);
            }
        }
}

// ---------------- fused windowed attention (KV precomputed) ----------------
// grid 4096, block 512 (8 waves: head s=w&3, row-half hf=w>>2).
// dst = src + reverse(proj(attn(LN(src)@wq, K_win, V_win))).
__global__ __launch_bounds__(512, 4) void k_win_attn2(
    const float* src, float* dst, const u16* __restrict__ KV, int kvoff,
    const float* __restrict__ lng, const float* __restrict__ lnb,
    const u16* __restrict__ wqT, const u16* __restrict__ wpT,
    const float* __restrict__ bq, const float* __restrict__ bp,
    const float* __restrict__ rpb, int shift)
{
    // A: yL -> V(token-major)   (25,872 B @ 0)
    // B: qL -> P[4][49][72]     (28,224 B @ 25,872)
    // C: kL -> O                (25,872 B @ 54,096)
    __shared__ __align__(16) char smem[80384];
    u16* tA = (u16*)(smem);
    u16* tB = (u16*)(smem + 25872);
    u16* tC = (u16*)(smem + 54096);
    int* t_idx = (int*)(smem + 79968);
    int* label = (int*)(smem + 80164);

    const int tid = threadIdx.x, lane = tid & 63;
    const int w = tid >> 6;
    const int s  = w & 3;        // head / col strip
    const int hf = w >> 2;       // row half
    const int mtb = hf * 2;
    const int l15 = lane & 15, g = lane >> 4, kg = g * 8;
    const int nb = s * 64;

    const int wi = blockIdx.x;
    const int b  = wi >> 10;
    const int wl = wi & 1023;
    const int wh = wl >> 5, wwi = wl & 31;

    if (tid < NTOK) {
        int yi = tid / 7, xi = tid - yi * 7;
        int h = wh * 7 + yi + shift; if (h >= 224) h -= 224;
        int ww = wwi * 7 + xi + shift; if (ww >= 224) ww -= 224;
        t_idx[tid] = (b * 224 + h) * 224 + ww;
        int hp = wh * 7 + yi, wp = wwi * 7 + xi;
        int rh = (hp < 217) ? 0 : ((hp < 221) ? 1 : 2);
        int rw = (wp < 217) ? 0 : ((wp < 221) ? 1 : 2);
        label[tid] = rh * 3 + rw;
    }
    __syncthreads();

    // ---- p1: waves 0-3: LN(src) -> tA ; waves 4-7: stage K window -> tC ----
    if (hf == 0) {
        for (int r = s; r < NTOK; r += 4) {
            const float4 xv = *(const float4*)(src + (size_t)t_idx[r] * 256 + lane * 4);
            float xs[4] = {xv.x, xv.y, xv.z, xv.w};
            float sm = xs[0] + xs[1] + xs[2] + xs[3];
            float s2 = xs[0] * xs[0] + xs[1] * xs[1] + xs[2] * xs[2] + xs[3] * xs[3];
#pragma unroll
            for (int m = 1; m < 64; m <<= 1) { sm += __shfl_xor(sm, m); s2 += __shfl_xor(s2, m); }
            float mean = sm * (1.0f / 256.0f);
            float var = s2 * (1.0f / 256.0f) - mean * mean;
            float rstd = rsqrtf(fmaxf(var, 0.0f) + 1e-12f);
#pragma unroll
            for (int j = 0; j < 4; ++j) {
                int c = lane * 4 + j;
                float yv = (xs[j] - mean) * rstd * lng[c] + lnb[c];
                tA[r * SA + c] = f2bf(yv);
            }
        }
    } else {
        for (int r = s; r < NTOK; r += 4)
            *(ushort4*)(tC + r * SA + lane * 4) =
                *(const ushort4*)(KV + (size_t)t_idx[r] * 1024 + kvoff + lane * 4);
    }
    __syncthreads();

    // ---- p2: Q = (yL @ wq + bq) * scale -> tB ----
    {
        f32x4 acc[2][4] = {};
        gemm49h(tA, wqT, nb, mtb, lane, acc);
#pragma unroll
        for (int m = 0; m < 2; ++m)
#pragma unroll
            for (int nt = 0; nt < 4; ++nt) {
                int col = nb + nt * 16 + l15;
                float bias = bq[col];
#pragma unroll
                for (int r = 0; r < 4; ++r) {
                    int row = (mtb + m) * 16 + g * 4 + r;
                    if (row < NTOK) tB[row * SA + col] = f2bf((acc[m][nt][r] + bias) * 0.125f);
                }
            }
    }
    __syncthreads();   // qL ready; yL reads done (tA reusable)

    // ---- p3: stage V window -> tA ; S = qk^T + bias(+mask); softmax in regs ----
    for (int r = w; r < NTOK; r += 8)
        *(ushort4*)(tA + r * SA + lane * 4) =
            *(const ushort4*)(KV + (size_t)t_idx[r] * 1024 + kvoff + 256 + lane * 4);

    f32x4 sa[2][4] = {};
    {
        const int h = s;
        const bf16x8 z = zfrag();
        for (int k0 = 0; k0 < 64; k0 += 32) {
            bf16x8 a[2], bb[4];
#pragma unroll
            for (int m = 0; m < 2; ++m) {
                int row = (mtb + m) * 16 + l15;
                a[m] = (row < NTOK) ? *(const bf16x8*)(tB + row * SA + h * 64 + k0 + kg) : z;
            }
#pragma unroll
            for (int nt = 0; nt < 4; ++nt) {
                int col = nt * 16 + l15;
                bb[nt] = (col < NTOK) ? *(const bf16x8*)(tC + col * SA + h * 64 + k0 + kg) : z;
            }
#pragma unroll
            for (int m = 0; m < 2; ++m)
#pragma unroll
                for (int nt = 0; nt < 4; ++nt)
                    sa[m][nt] = __builtin_amdgcn_mfma_f32_16x16x32_bf16(a[m], bb[nt], sa[m][nt], 0, 0, 0);
        }
#pragma unroll
        for (int m = 0; m < 2; ++m) {
#pragma unroll
            for (int rr = 0; rr < 4; ++rr) {
                int i = (mtb + m) * 16 + g * 4 + rr;
                bool iv = (i < NTOK);
                int yi = iv ? (i / 7) : 0, xi = iv ? (i - (i / 7) * 7) : 0;
                int li = iv ? label[i] : 0;
                float v[4], mx = -1e30f;
#pragma unroll
                for (int nt = 0; nt < 4; ++nt) {
                    int j = nt * 16 + l15;
                    float t = -1e30f;
                    if (iv && j < NTOK) {
                        t = sa[m][nt][rr];
                        int yj = j / 7, xj = j - (j / 7) * 7;
                        t += rpb[((yi - yj + 6) * 13 + (xi - xj + 6)) * 4 + h];
                        if (shift > 0 && li != label[j]) t -= 100.0f;
                    }
                    v[nt] = t;
                    mx = fmaxf(mx, t);
                }
#pragma unroll
                for (int mk = 1; mk < 16; mk <<= 1) mx = fmaxf(mx, __shfl_xor(mx, mk));
                float sum = 0.f, e[4];
#pragma unroll
                for (int nt = 0; nt < 4; ++nt) {
                    e[nt] = (v[nt] > -1e29f) ? __expf(v[nt] - mx) : 0.0f;
                    sum += e[nt];
                }
#pragma unroll
                for (int mk = 1; mk < 16; mk <<= 1) sum += __shfl_xor(sum, mk);
                float inv = 1.0f / sum;
#pragma unroll
                for (int nt = 0; nt < 4; ++nt) sa[m][nt][rr] = e[nt] * inv;
            }
        }
    }
    __syncthreads();   // qL/kL reads done; V staged

    // ---- p4: store P -> tB ; O = P @ V -> tC ----
    {
        const int h = s;
#pragma unroll
        for (int m = 0; m < 2; ++m)
#pragma unroll
            for (int rr = 0; rr < 4; ++rr) {
                int i = (mtb + m) * 16 + g * 4 + rr;
                if (i < NTOK) {
                    u16* Prow = tB + h * (NTOK * SP) + i * SP;
#pragma unroll
                    for (int nt = 0; nt < 4; ++nt) Prow[nt * 16 + l15] = f2bf(sa[m][nt][rr]);
                }
            }
        // PV: each wave reads only P rows it wrote (wave-internal LDS RAW is safe)
        const bf16x8 z = zfrag();
        f32x4 oa[2][4] = {};
        for (int k0 = 0; k0 < 64; k0 += 32) {
            bf16x8 a[2], bb[4];
#pragma unroll
            for (int m = 0; m < 2; ++m) {
                int row = (mtb + m) * 16 + l15;
                a[m] = (row < NTOK) ? *(const bf16x8*)(tB + h * (NTOK * SP) + row * SP + k0 + kg) : z;
            }
#pragma unroll
            for (int nt = 0; nt < 4; ++nt) {
                u16 tmp[8];
#pragma unroll
                for (int i = 0; i < 8; ++i) {
                    int tok = k0 + kg + i;
                    tmp[i] = (tok < NTOK) ? tA[tok * SA + h * 64 + nt * 16 + l15] : (u16)0;
                }
                bb[nt] = *(bf16x8*)tmp;
            }
#pragma unroll
            for (int m = 0; m < 2; ++m)
#pragma unroll
                for (int nt = 0; nt < 4; ++nt)
                    oa[m][nt] = __builtin_amdgcn_mfma_f32_16x16x32_bf16(a[m], bb[nt], oa[m][nt], 0, 0, 0);
        }
#pragma unroll
        for (int m = 0; m < 2; ++m)
#pragma unroll
            for (int nt = 0; nt < 4; ++nt) {
                int col = h * 64 + nt * 16 + l15;
#pragma unroll
                for (int r = 0; r < 4; ++r) {
                    int row = (mtb + m) * 16 + g * 4 + r;
                    if (row < NTOK) tC[row * SA + col] = f2bf(oa[m][nt][r]);
                }
            }
    }
    __syncthreads();   // O complete

    // ---- p5: dst = src + O @ Wp + bp ----
    {
        f32x4 acc[2][4] = {};
        gemm49h(tC, wpT, nb, mtb, lane, acc);
#pragma unroll
        for (int m = 0; m < 2; ++m)
#pragma unroll
            for (int nt = 0; nt < 4; ++nt) {
                int col = nb + nt * 16 + l15;
                float bias = bp[col];
#pragma unroll
                for (int r = 0; r < 4; ++r) {
                    int row = (mtb + m) * 16 + g * 4 + r;
                    if (row < NTOK) {
                        size_t off = (size_t)t_idx[row] * 256 + col;
                        dst[off] = src[off] + acc[m][nt][r] + bias;
                    }
                }
            }
    }
}

// ---------------- round-5 fused attention (fallback when ws too small) ----------------
__global__ __launch_bounds__(512, 4) void k_win_attn_fb(
    const float* src, float* dst, const float* __restrict__ enc,
    const float* __restrict__ lng, const float* __restrict__ lnb,
    const u16* __restrict__ wqT, const u16* __restrict__ wkT,
    const u16* __restrict__ wvT, const u16* __restrict__ wpT,
    const float* __restrict__ bq, const float* __restrict__ bk,
    const float* __restrict__ bv, const float* __restrict__ bp,
    const float* __restrict__ rpb, int shift)
{
    __shared__ __align__(16) char smem[80384];
    u16* tA = (u16*)(smem);
    u16* tB = (u16*)(smem + 25872);
    u16* tC = (u16*)(smem + 54096);
    int* t_idx = (int*)(smem + 79968);
    int* label = (int*)(smem + 80164);

    const int tid = threadIdx.x, lane = tid & 63;
    const int w = tid >> 6;
    const int s  = w & 3;
    const int hf = w >> 2;
    const int mtb = hf * 2;
    const int l15 = lane & 15, g = lane >> 4, kg = g * 8;
    const int nb = s * 64;

    const int wi = blockIdx.x;
    const int b  = wi >> 10;
    const int wl = wi & 1023;
    const int wh = wl >> 5, wwi = wl & 31;

    if (tid < NTOK) {
        int yi = tid / 7, xi = tid - yi * 7;
        int h = wh * 7 + yi + shift; if (h >= 224) h -= 224;
        int ww = wwi * 7 + xi + shift; if (ww >= 224) ww -= 224;
        t_idx[tid] = (b * 224 + h) * 224 + ww;
        int hp = wh * 7 + yi, wp = wwi * 7 + xi;
        int rh = (hp < 217) ? 0 : ((hp < 221) ? 1 : 2);
        int rw = (wp < 217) ? 0 : ((wp < 221) ? 1 : 2);
        label[tid] = rh * 3 + rw;
    }
    __syncthreads();

    for (int r = w; r < NTOK; r += 8) {
        const float4 xv = *(const float4*)(src + (size_t)t_idx[r] * 256 + lane * 4);
        float xs[4] = {xv.x, xv.y, xv.z, xv.w};
        float sm = xs[0] + xs[1] + xs[2] + xs[3];
        float s2 = xs[0] * xs[0] + xs[1] * xs[1] + xs[2] * xs[2] + xs[3] * xs[3];
#pragma unroll
        for (int m = 1; m < 64; m <<= 1) { sm += __shfl_xor(sm, m); s2 += __shfl_xor(s2, m); }
        float mean = sm * (1.0f / 256.0f);
        float var = s2 * (1.0f / 256.0f) - mean * mean;
        float rstd = rsqrtf(fmaxf(var, 0.0f) + 1e-12f);
#pragma unroll
        for (int j = 0; j < 4; ++j) {
            int c = lane * 4 + j;
            tA[r * SA + c] = f2bf((xs[j] - mean) * rstd * lng[c] + lnb[c]);
        }
    }
    __syncthreads();

    {
        f32x4 acc[2][4] = {};
        gemm49h(tA, wqT, nb, mtb, lane, acc);
#pragma unroll
        for (int m = 0; m < 2; ++m)
#pragma unroll
            for (int nt = 0; nt < 4; ++nt) {
                int col = nb + nt * 16 + l15;
                float bias = bq[col];
#pragma unroll
                for (int r = 0; r < 4; ++r) {
                    int row = (mtb + m) * 16 + g * 4 + r;
                    if (row < NTOK) tB[row * SA + col] = f2bf((acc[m][nt][r] + bias) * 0.125f);
                }
            }
    }
    __syncthreads();

    for (int idx = tid; idx < NTOK * 32; idx += 512) {
        int r = idx >> 5, c8 = (idx & 31) << 3;
        const float* ep = enc + (size_t)t_idx[r] * 256 + c8;
        const float4 v0 = *(const float4*)(ep);
        const float4 v1 = *(const float4*)(ep + 4);
        u16* p = tA + r * SA + c8;
        p[0] = f2bf(v0.x); p[1] = f2bf(v0.y); p[2] = f2bf(v0.z); p[3] = f2bf(v0.w);
        p[4] = f2bf(v1.x); p[5] = f2bf(v1.y); p[6] = f2bf(v1.z); p[7] = f2bf(v1.w);
    }
    __syncthreads();

    {
        f32x4 acc[2][4] = {};
        gemm49h(tA, wkT, nb, mtb, lane, acc);
#pragma unroll
        for (int m = 0; m < 2; ++m)
#pragma unroll
            for (int nt = 0; nt < 4; ++nt) {
                int col = nb + nt * 16 + l15;
                float bias = bk[col];
#pragma unroll
                for (int r = 0; r < 4; ++r) {
                    int row = (mtb + m) * 16 + g * 4 + r;
                    if (row < NTOK) tC[row * SA + col] = f2bf(acc[m][nt][r] + bias);
                }
            }
    }
    __syncthreads();

    f32x4 vacc[2][4] = {};
    gemm49h(tA, wvT, nb, mtb, lane, vacc);

    f32x4 sa[2][4] = {};
    {
        const int h = s;
        const bf16x8 z = zfrag();
        for (int k0 = 0; k0 < 64; k0 += 32) {
            bf16x8 a[2], bb[4];
#pragma unroll
            for (int m = 0; m < 2; ++m) {
                int row = (mtb + m) * 16 + l15;
                a[m] = (row < NTOK) ? *(const bf16x8*)(tB + row * SA + h * 64 + k0 + kg) : z;
            }
#pragma unroll
            for (int nt = 0; nt < 4; ++nt) {
                int col = nt * 16 + l15;
                bb[nt] = (col < NTOK) ? *(const bf16x8*)(tC + col * SA + h * 64 + k0 + kg) : z;
            }
#pragma unroll
            for (int m = 0; m < 2; ++m)
#pragma unroll
                for (int nt = 0; nt < 4; ++nt)
                    sa[m][nt] = __builtin_amdgcn_mfma_f32_16x16x32_bf16(a[m], bb[nt], sa[m][nt], 0, 0, 0);
        }
#pragma unroll
        for (int m = 0; m < 2; ++m) {
#pragma unroll
            for (int rr = 0; rr < 4; ++rr) {
                int i = (mtb + m) * 16 + g * 4 + rr;
                bool iv = (i < NTOK);
                int yi = iv ? (i / 7) : 0, xi = iv ? (i - (i / 7) * 7) : 0;
                int li = iv ? label[i] : 0;
                float v[4], mx = -1e30f;
#pragma unroll
                for (int nt = 0; nt < 4; ++nt) {
                    int j = nt * 16 + l15;
                    float t = -1e30f;
                    if (iv && j < NTOK) {
                        t = sa[m][nt][rr];
                        int yj = j / 7, xj = j - (j / 7) * 7;
                        t += rpb[((yi - yj + 6) * 13 + (xi - xj + 6)) * 4 + h];
                        if (shift > 0 && li != label[j]) t -= 100.0f;
                    }
                    v[nt] = t;
                    mx = fmaxf(mx, t);
                }
#pragma unroll
                for (int mk = 1; mk < 16; mk <<= 1) mx = fmaxf(mx, __shfl_xor(mx, mk));
                float sum = 0.f, e[4];
#pragma unroll
                for (int nt = 0; nt < 4; ++nt) {
                    e[nt] = (v[nt] > -1e29f) ? __expf(v[nt] - mx) : 0.0f;
                    sum += e[nt];
                }
#pragma unroll
                for (int mk = 1; mk < 16; mk <<= 1) sum += __shfl_xor(sum, mk);
                float inv = 1.0f / sum;
#pragma unroll
                for (int nt = 0; nt < 4; ++nt) sa[m][nt][rr] = e[nt] * inv;
            }
        }
    }
    __syncthreads();

    {
        const int h = s;
#pragma unroll
        for (int m = 0; m < 2; ++m)
#pragma unroll
            for (int rr = 0; rr < 4; ++rr) {
                int i = (mtb + m) * 16 + g * 4 + rr;
                if (i < NTOK) {
                    u16* Prow = tB + h * (NTOK * SP) + i * SP;
#pragma unroll
                    for (int nt = 0; nt < 4; ++nt) Prow[nt * 16 + l15] = f2bf(sa[m][nt][rr]);
                }
            }
#pragma unroll
        for (int m = 0; m < 2; ++m)
#pragma unroll
            for (int nt = 0; nt < 4; ++nt) {
                int col = nb + nt * 16 + l15;
                float bias = bv[col];
#pragma unroll
                for (int r = 0; r < 4; ++r) {
                    int row = (mtb + m) * 16 + g * 4 + r;
                    if (row < NTOK) tC[row * SA + col] = f2bf(vacc[m][nt][r] + bias);
                }
            }
    }
    __syncthreads();

    {
        const int h = s;
        const bf16x8 z = zfrag();
        f32x4 oa[2][4] = {};
        for (int k0 = 0; k0 < 64; k0 += 32) {
            bf16x8 a[2], bb[4];
#pragma unroll
            for (int m = 0; m < 2; ++m) {
                int row = (mtb + m) * 16 + l15;
                a[m] = (row < NTOK) ? *(const bf16x8*)(tB + h * (NTOK * SP) + row * SP + k0 + kg) : z;
            }
#pragma unroll
            for (int nt = 0; nt < 4; ++nt) {
                u16 tmp[8];
#pragma unroll
                for (int i = 0; i < 8; ++i) {
                    int tok = k0 + kg + i;
                    tmp[i] = (tok < NTOK) ? tC[tok * SA + h * 64 + nt * 16 + l15] : (u16)0;
                }
                bb[nt] = *(bf16x8*)tmp;
            }
#pragma unroll
            for (int m = 0; m < 2; ++m)
#pragma unroll
                for (int nt = 0; nt < 4; ++nt)
                    oa[m][nt] = __builtin_amdgcn_mfma_f32_16x16x32_bf16(a[m], bb[nt], oa[m][nt], 0, 0, 0);
        }
        __syncthreads();
#pragma unroll
        for (int m = 0; m < 2; ++m)
#pragma unroll
            for (int nt = 0; nt < 4; ++nt) {
                int col = h * 64 + nt * 16 + l15;
#pragma unroll
                for (int r = 0; r < 4; ++r) {
                    int row = (mtb + m) * 16 + g * 4 + r;
                    if (row < NTOK) tA[row * SA + col] = f2bf(oa[m][nt][r]);
                }
            }
    }
    __syncthreads();

    {
        f32x4 acc[2][4] = {};
        gemm49h(tA, wpT, nb, mtb, lane, acc);
#pragma unroll
        for (int m = 0; m < 2; ++m)
#pragma unroll
            for (int nt = 0; nt < 4; ++nt) {
                int col = nb + nt * 16 + l15;
                float bias = bp[col];
#pragma unroll
                for (int r = 0; r < 4; ++r) {
                    int row = (mtb + m) * 16 + g * 4 + r;
                    if (row < NTOK) {
                        size_t off = (size_t)t_idx[row] * 256 + col;
                        dst[off] = src[off] + acc[m][nt][r] + bias;
                    }
                }
            }
    }
}

// ---------------- fused MLP (in place): R = R + fc2(gelu(fc1(LN(R)))) ----------------
// grid T_TOK/64, block 512 (8 waves: n-strip s2=w&3, row-half hf=w>>2).
#define SM 264
__global__ __launch_bounds__(512, 4) void k_mlp(
    float* R,
    const float* __restrict__ lng, const float* __restrict__ lnb,
    const u16* __restrict__ fc1T, const float* __restrict__ fc1b,
    const u16* __restrict__ fc2T, const float* __restrict__ fc2b)
{
    __shared__ __align__(16) u16 yL[64 * SM];
    __shared__ __align__(16) u16 hL[64 * SM];
    const int tid = threadIdx.x, lane = tid & 63, w = tid >> 6;
    const int s2 = w & 3, hf = w >> 2, mtb = hf * 2;
    const int l15 = lane & 15, g = lane >> 4, kg = g * 8;
    const size_t t0 = (size_t)blockIdx.x * 64;
    const int nb = s2 * 64;

    for (int r = w; r < 64; r += 8) {
        const float4 xv = *(const float4*)(R + (t0 + r) * 256 + lane * 4);
        float xs[4] = {xv.x, xv.y, xv.z, xv.w};
        float s = xs[0] + xs[1] + xs[2] + xs[3];
        float s2s = xs[0] * xs[0] + xs[1] * xs[1] + xs[2] * xs[2] + xs[3] * xs[3];
#pragma unroll
        for (int m = 1; m < 64; m <<= 1) { s += __shfl_xor(s, m); s2s += __shfl_xor(s2s, m); }
        float mean = s * (1.0f / 256.0f);
        float var = s2s * (1.0f / 256.0f) - mean * mean;
        float rstd = rsqrtf(fmaxf(var, 0.0f) + 1e-12f);
#pragma unroll
        for (int j = 0; j < 4; ++j) {
            int c = lane * 4 + j;
            yL[r * SM + c] = f2bf((xs[j] - mean) * rstd * lng[c] + lnb[c]);
        }
    }
    __syncthreads();

    f32x4 acc2[2][4] = {};
    for (int ch = 0; ch < 4; ++ch) {
        f32x4 acc1[2][4] = {};
        for (int k0 = 0; k0 < 256; k0 += 32) {
            bf16x8 a[2], bb[4];
#pragma unroll
            for (int m = 0; m < 2; ++m)
                a[m] = *(const bf16x8*)(yL + ((mtb + m) * 16 + l15) * SM + k0 + kg);
#pragma unroll
            for (int nt = 0; nt < 4; ++nt) {
                int hidx = ch * 256 + nb + nt * 16 + l15;
                bb[nt] = *(const bf16x8*)(fc1T + (size_t)hidx * 256 + k0 + kg);
            }
#pragma unroll
            for (int m = 0; m < 2; ++m)
#pragma unroll
                for (int nt = 0; nt < 4; ++nt)
                    acc1[m][nt] = __builtin_amdgcn_mfma_f32_16x16x32_bf16(a[m], bb[nt], acc1[m][nt], 0, 0, 0);
        }
#pragma unroll
        for (int m = 0; m < 2; ++m)
#pragma unroll
            for (int nt = 0; nt < 4; ++nt) {
                int hcol = nb + nt * 16 + l15;
                float bias = fc1b[ch * 256 + hcol];
#pragma unroll
                for (int r = 0; r < 4; ++r) {
                    int row = (mtb + m) * 16 + g * 4 + r;
                    float v = acc1[m][nt][r] + bias;
                    v = 0.5f * v * (1.0f + erff(v * 0.70710678f));
                    hL[row * SM + hcol] = f2bf(v);
                }
            }
        __syncthreads();
        for (int k0 = 0; k0 < 256; k0 += 32) {
            bf16x8 a[2], bb[4];
#pragma unroll
            for (int m = 0; m < 2; ++m)
                a[m] = *(const bf16x8*)(hL + ((mtb + m) * 16 + l15) * SM + k0 + kg);
#pragma unroll
            for (int nt = 0; nt < 4; ++nt) {
                int col = nb + nt * 16 + l15;
                bb[nt] = *(const bf16x8*)(fc2T + (size_t)col * 1024 + ch * 256 + k0 + kg);
            }
#pragma unroll
            for (int m = 0; m < 2; ++m)
#pragma unroll
                for (int nt = 0; nt < 4; ++nt)
                    acc2[m][nt] = __builtin_amdgcn_mfma_f32_16x16x32_bf16(a[m], bb[nt], acc2[m][nt], 0, 0, 0);
        }
        __syncthreads();
    }
#pragma unroll
    for (int m = 0; m < 2; ++m)
#pragma unroll
        for (int nt = 0; nt < 4; ++nt) {
            int col = nb + nt * 16 + l15;
            float bias = fc2b[col];
#pragma unroll
            for (int r = 0; r < 4; ++r) {
                int row = (mtb + m) * 16 + g * 4 + r;
                size_t off = (t0 + row) * 256 + col;
                R[off] = acc2[m][nt][r] + bias + R[off];
            }
        }
}

extern "C" void kernel_launch(void* const* d_in, const int* in_sizes, int n_in,
                              void* d_out, int out_size, void* d_ws, size_t ws_size,
                              hipStream_t stream) {
    (void)in_sizes; (void)n_in; (void)out_size;
    u16* WTbase = (u16*)d_ws;
    u16* wT[8];
    for (int i = 0; i < 8; ++i) wT[i] = WTbase + (size_t)i * 65536;
    u16* fc1T = WTbase + (size_t)8 * 65536;      // [1024][256]
    u16* fc2T = fc1T + 262144;                   // [256][1024]
    u16* KV = WTbase + 1048576;                  // [T_TOK][1024] bf16 (411 MB)
    const size_t need = 2u * 1024 * 1024 + (size_t)T_TOK * 1024 * 2;
    const bool big = (ws_size >= need);

    const int wsrc[8] = {10, 11, 12, 13, 19, 20, 21, 22};
    for (int i = 0; i < 8; ++i)
        k_transpose<<<256, 256, 0, stream>>>((const float*)d_in[wsrc[i]], wT[i], 256, 256);
    k_transpose<<<1024, 256, 0, stream>>>((const float*)d_in[28], fc1T, 256, 1024);
    k_transpose<<<1024, 256, 0, stream>>>((const float*)d_in[30], fc2T, 1024, 256);

    float* R = (float*)d_out;   // fp32 residual stream in d_out

    if (big) {
        dim3 gkv(T_TOK / 64, 4);
        k_kv<<<gkv, 256, 0, stream>>>((const float*)d_in[1], KV,
            wT[1], wT[2], wT[5], wT[6],
            (const float*)d_in[15], (const float*)d_in[16],
            (const float*)d_in[24], (const float*)d_in[25]);
        k_win_attn2<<<4096, 512, 0, stream>>>((const float*)d_in[0], R, KV, 0,
            (const float*)d_in[4], (const float*)d_in[5], wT[0], wT[3],
            (const float*)d_in[14], (const float*)d_in[17], (const float*)d_in[18], 0);
        k_win_attn2<<<4096, 512, 0, stream>>>(R, R, KV, 512,
            (const float*)d_in[6], (const float*)d_in[7], wT[4], wT[7],
            (const float*)d_in[23], (const float*)d_in[26], (const float*)d_in[27], 3);
    } else {
        k_win_attn_fb<<<4096, 512, 0, stream>>>((const float*)d_in[0], R, (const float*)d_in[1],
            (const float*)d_in[4], (const float*)d_in[5],
            wT[0], wT[1], wT[2], wT[3],
            (const float*)d_in[14], (const float*)d_in[15], (const float*)d_in[16], (const float*)d_in[17],
            (const float*)d_in[18], 0);
        k_win_attn_fb<<<4096, 512, 0, stream>>>(R, R, (const float*)d_in[1],
            (const float*)d_in[6], (const float*)d_in[7],
            wT[4], wT[5], wT[6], wT[7],
            (const float*)d_in[23], (const float*)d_in[24], (const float*)d_in[25], (const float*)d_in[26],
            (const float*)d_in[27], 3);
    }
    k_mlp<<<T_TOK / 64, 512, 0, stream>>>(R,
        (const float*)d_in[8], (const float*)d_in[9],
        fc1T, (const float*)d_in[29], fc2T, (const float*)d_in[31]);
}